// Round 1
// baseline (1667.817 us; speedup 1.0000x reference)
//
#include <hip/hip_runtime.h>
#include <stdint.h>

// ---------------------------------------------------------------------------
// FasterRCNN head on MI355X.
// Pipeline: mask scores -> radix-select 6000th -> compact -> bitonic sort
//           -> greedy NMS (300) -> ROIAlign (bf16) -> fc1/fc2 (bf16 MFMA,
//           split-K, fused fp32->bf16 weight conversion) -> cls/reg head
//           -> softmax + decode.
// ---------------------------------------------------------------------------

#define NEGV -1e30f

typedef __attribute__((ext_vector_type(8))) short short8;
typedef __attribute__((ext_vector_type(4))) float f32x4;

__device__ __forceinline__ uint16_t f2bf(float f) {
  uint32_t u = __builtin_bit_cast(uint32_t, f);
  u = (u + 0x7FFFu + ((u >> 16) & 1u)) >> 16;
  return (uint16_t)u;
}
__device__ __forceinline__ float bf2f(uint16_t h) {
  return __builtin_bit_cast(float, ((uint32_t)h) << 16);
}
// monotone float -> uint32 key (order-preserving for all finite floats)
__device__ __forceinline__ uint32_t fkey(float f) {
  uint32_t u = __builtin_bit_cast(uint32_t, f);
  return (u & 0x80000000u) ? ~u : (u | 0x80000000u);
}

// ---------------------------------------------------------------------------
// 1) score mask + key build; also init sort buffer + atomic counter
// ---------------------------------------------------------------------------
__global__ __launch_bounds__(256) void prep_kernel(
    const float* __restrict__ proposals, const float* __restrict__ scores,
    uint32_t* __restrict__ keys, uint64_t* __restrict__ sortbuf,
    int* __restrict__ counter) {
  int i = blockIdx.x * 256 + threadIdx.x;
  if (i < 8192) sortbuf[i] = 0ULL;  // sentinel: below every real entry
  if (i == 0) *counter = 0;
  if (i < 22500) {
    float w = proposals[i * 4 + 2], h = proposals[i * 4 + 3];
    float s = scores[i];
    s = (w < 16.0f || h < 16.0f) ? NEGV : s;
    keys[i] = fkey(s);
  }
}

// ---------------------------------------------------------------------------
// 2) radix select: exact key value of the 6000th largest
// ---------------------------------------------------------------------------
__global__ __launch_bounds__(1024) void select_kernel(
    const uint32_t* __restrict__ keys, uint32_t* __restrict__ cutoff) {
  __shared__ uint32_t hist[256];
  __shared__ uint32_t s_prefix;
  __shared__ int s_remaining;
  int tid = threadIdx.x;
  if (tid == 0) { s_prefix = 0; s_remaining = 6000; }
  __syncthreads();
  for (int round = 0; round < 4; round++) {
    int shift = 24 - round * 8;
    for (int i = tid; i < 256; i += 1024) hist[i] = 0;
    __syncthreads();
    uint32_t prefix = s_prefix;
    uint32_t pmask = (round == 0) ? 0u : (0xFFFFFFFFu << (shift + 8));
    for (int i = tid; i < 22500; i += 1024) {
      uint32_t kv = keys[i];
      if ((kv & pmask) == (prefix & pmask))
        atomicAdd(&hist[(kv >> shift) & 255u], 1u);
    }
    __syncthreads();
    if (tid == 0) {
      int rem = s_remaining;
      int chosen = 0;
      for (int b = 255; b >= 0; b--) {
        int c = (int)hist[b];
        if (c >= rem) { chosen = b; break; }
        rem -= c;
      }
      s_prefix = prefix | ((uint32_t)chosen << shift);
      s_remaining = rem;
    }
    __syncthreads();
  }
  if (tid == 0) *cutoff = s_prefix;
}

// ---------------------------------------------------------------------------
// 3) compact all entries with key >= cutoff  (6000 + a few ties at most)
// ---------------------------------------------------------------------------
__global__ __launch_bounds__(256) void compact_kernel(
    const uint32_t* __restrict__ keys, const uint32_t* __restrict__ cutoff,
    uint64_t* __restrict__ sortbuf, int* __restrict__ counter) {
  int i = blockIdx.x * 256 + threadIdx.x;
  if (i >= 22500) return;
  uint32_t kv = keys[i];
  if (kv >= *cutoff) {
    int p = atomicAdd(counter, 1);
    if (p < 8192)
      sortbuf[p] = ((uint64_t)kv << 32) | (uint32_t)(~(uint32_t)i);
  }
}

// ---------------------------------------------------------------------------
// 4) single-block bitonic sort of 8192 (desc by score, asc by index) -> top6000
// ---------------------------------------------------------------------------
__global__ __launch_bounds__(1024) void sort_kernel(
    const uint64_t* __restrict__ sortbuf, int* __restrict__ sorted_idx) {
  __shared__ uint64_t v[8192];
  int tid = threadIdx.x;
  for (int i = tid; i < 8192; i += 1024) v[i] = sortbuf[i];
  __syncthreads();
  for (int k = 2; k <= 8192; k <<= 1) {
    for (int j = k >> 1; j > 0; j >>= 1) {
      for (int i = tid; i < 8192; i += 1024) {
        int ixj = i ^ j;
        if (ixj > i) {
          uint64_t a = v[i], b = v[ixj];
          bool up = (i & k) == 0;  // descending overall
          if (up ? (a < b) : (a > b)) { v[i] = b; v[ixj] = a; }
        }
      }
      __syncthreads();
    }
  }
  for (int i = tid; i < 6000; i += 1024)
    sorted_idx[i] = (int)(~(uint32_t)(v[i] & 0xFFFFFFFFull));
}

// ---------------------------------------------------------------------------
// 5) gather sorted boxes: xywh + xyxy
// ---------------------------------------------------------------------------
__global__ __launch_bounds__(256) void gather_kernel(
    const float* __restrict__ proposals, const int* __restrict__ sorted_idx,
    float4* __restrict__ sxyxy, float4* __restrict__ sxywh) {
  int i = blockIdx.x * 256 + threadIdx.x;
  if (i >= 6000) return;
  int oi = sorted_idx[i];
  float x = proposals[oi * 4 + 0], y = proposals[oi * 4 + 1];
  float w = proposals[oi * 4 + 2], h = proposals[oi * 4 + 3];
  sxywh[i] = make_float4(x, y, w, h);
  sxyxy[i] = make_float4(x, y, x + w, y + h);  // single adds: exact vs ref
}

// ---------------------------------------------------------------------------
// 6) greedy NMS over sorted order; keep 300 positions
//    IoU must match reference fp32 op-for-op -> contraction OFF here.
// ---------------------------------------------------------------------------
__global__ __launch_bounds__(1024) void nms_kernel(
    const float4* __restrict__ sxyxy, const float4* __restrict__ sxywh,
    float4* __restrict__ keep_xyxy, float4* __restrict__ keep_xywh) {
#pragma clang fp contract(off)
  __shared__ unsigned char flags[6000];
  __shared__ int keep_list[300];
  __shared__ int s_pos;
  __shared__ float4 s_box;
  int tid = threadIdx.x;
  for (int i = tid; i < 6000; i += 1024) flags[i] = 0;
  __shared__ int s_ptr;
  if (tid == 0) s_ptr = 0;
  __syncthreads();
  for (int kept = 0; kept < 300; kept++) {
    if (tid == 0) {
      int p = s_ptr;
      while (p < 6000 && flags[p]) p++;
      if (p < 6000) {
        keep_list[kept] = p;
        s_pos = p;
        s_ptr = p + 1;
        s_box = sxyxy[p];
      } else {
        keep_list[kept] = 0;  // reference argmax-over-all-NEG fallback
        s_pos = -1;
        s_ptr = p;
      }
    }
    __syncthreads();
    int pos = s_pos;
    if (pos >= 0) {
      float4 bb = s_box;
      float ba = (bb.z - bb.x) * (bb.w - bb.y);
      for (int j = pos + 1 + tid; j < 6000; j += 1024) {
        if (flags[j]) continue;
        float4 ob = sxyxy[j];
        float xx1 = fmaxf(bb.x, ob.x);
        float yy1 = fmaxf(bb.y, ob.y);
        float xx2 = fminf(bb.z, ob.z);
        float yy2 = fminf(bb.w, ob.w);
        float inter = fmaxf(xx2 - xx1, 0.0f) * fmaxf(yy2 - yy1, 0.0f);
        float oa = (ob.z - ob.x) * (ob.w - ob.y);
        float iou = inter / (ba + oa - inter + 1e-9f);
        if (iou > 0.7f) flags[j] = 1;
      }
    }
    __syncthreads();
  }
  for (int i = tid; i < 300; i += 1024) {
    int kp = keep_list[i];
    keep_xyxy[i] = sxyxy[kp];
    keep_xywh[i] = sxywh[kp];
  }
}

// ---------------------------------------------------------------------------
// 7) ROIAlign -> A matrix bf16 [320][25088]  (rows 300..319 zero pad)
//    k = c*49 + py*7 + px  (matches reshape order)
// ---------------------------------------------------------------------------
__global__ __launch_bounds__(256) void roi_kernel(
    const float* __restrict__ feat, const float4* __restrict__ keep_xyxy,
    uint16_t* __restrict__ A) {
  int r = blockIdx.x;
  int tid = threadIdx.x;
  uint16_t* out = A + (size_t)r * 25088;
  if (r >= 300) {
    for (int k = tid; k < 25088; k += 256) out[k] = 0;
    return;
  }
  __shared__ int xi0[14], xi1[14], yi0[14], yi1[14];
  __shared__ float wxs[14], wys[14];
  if (tid < 28) {
    int axis = tid / 14;  // 0 = x, 1 = y
    int t = tid % 14;
    int g = t >> 1, sxi = t & 1;
    float4 box = keep_xyxy[r];
    float lo = (axis ? box.y : box.x) * 0.0625f;
    float hi = (axis ? box.w : box.z) * 0.0625f;
    float bsz = (hi - lo) / 7.0f;
    float sub = ((float)sxi + 0.5f) * 0.5f;  // 0.25 / 0.75 exact
    float coord = lo + ((float)g + sub) * bsz;
    float f = floorf(coord);
    float frac = coord - f;
    int i0 = (int)f;
    i0 = min(max(i0, 0), 49);
    int i1 = min(i0 + 1, 49);
    if (axis == 0) { xi0[t] = i0; xi1[t] = i1; wxs[t] = frac; }
    else           { yi0[t] = i0; yi1[t] = i1; wys[t] = frac; }
  }
  __syncthreads();
  for (int k = tid; k < 25088; k += 256) {
    int c = k / 49;
    int pos = k - c * 49;
    int py = pos / 7, px = pos - py * 7;
    const float* fc = feat + (size_t)c * 2500;
    float val = 0.0f;
#pragma unroll
    for (int sy = 0; sy < 2; sy++) {
      int iy = py * 2 + sy;
      float wy = wys[iy];
      int y0 = yi0[iy], y1 = yi1[iy];
#pragma unroll
      for (int sx = 0; sx < 2; sx++) {
        int ix = px * 2 + sx;
        float wx = wxs[ix];
        int x0 = xi0[ix], x1 = xi1[ix];
        float v00 = fc[y0 * 50 + x0], v01 = fc[y0 * 50 + x1];
        float v10 = fc[y1 * 50 + x0], v11 = fc[y1 * 50 + x1];
        val += v00 * (1.0f - wy) * (1.0f - wx) + v01 * (1.0f - wy) * wx +
               v10 * wy * (1.0f - wx) + v11 * wy * wx;
      }
    }
    out[k] = f2bf(val * 0.25f);
  }
}

// ---------------------------------------------------------------------------
// 8) split-K bf16 MFMA GEMM:  P[s] += A[320,K_chunk] * W[K_chunk, 4096-col64]
//    A: bf16 row-major [320][K]; W: fp32 [K][4096] converted to bf16 in staging
//    grid (64 n-blocks, S splits), 256 threads (4 waves)
//    wave w: m-tiles 5w..5w+4 (80 rows) x 4 n-tiles (64 cols)
// ---------------------------------------------------------------------------
#define MTILES 5
#define NTILES 4
__global__ __launch_bounds__(256) void gemm_kernel(
    const uint16_t* __restrict__ A, const float* __restrict__ W,
    float* __restrict__ P, int K, int S) {
  __shared__ uint16_t As[320 * 32];  // packed [m][32], 64B rows
  __shared__ uint16_t Bs[64 * 40];   // [n][k] 80B rows (32 used + 8 pad)
  const int nb = blockIdx.x;
  const int s = blockIdx.y;
  const int kchunk = K / S;
  const int steps = kchunk >> 5;
  const int k0base = s * kchunk;
  const int tid = threadIdx.x;
  const int w = tid >> 6;
  const int l = tid & 63;
  const int q = l >> 4;
  const int l15 = l & 15;

  f32x4 acc[MTILES][NTILES];
#pragma unroll
  for (int i = 0; i < MTILES; i++)
#pragma unroll
    for (int j = 0; j < NTILES; j++) acc[i][j] = (f32x4)0.0f;

  const int ng = (tid & 15) << 2;  // n group of 4 for B staging
  const int kp = tid >> 4;         // k-pair 0..15

  for (int kk = 0; kk < steps; kk++) {
    const int k0 = k0base + (kk << 5);
    // stage A: 320 rows x 64B via global_load_lds (16B/lane, wave-uniform dst)
#pragma unroll
    for (int t = 0; t < 5; t++) {
      int cidx = w * 320 + t * 64 + l;     // 16B chunk id
      int m = cidx >> 2;
      int co = (cidx & 3) << 3;            // ushort offset in row
      const uint16_t* gp = A + (size_t)m * K + k0 + co;
      __builtin_amdgcn_global_load_lds(
          (const __attribute__((address_space(1))) void*)gp,
          (__attribute__((address_space(3))) void*)(As + (w * 320 + t * 64) * 8),
          16, 0, 0);
    }
    // stage B: 32 k-rows x 64 n fp32 -> bf16 transposed [n][k]
    {
      const float* wp = W + (size_t)(k0 + 2 * kp) * 4096 + nb * 64 + ng;
      f32x4 f0 = *(const f32x4*)wp;
      f32x4 f1 = *(const f32x4*)(wp + 4096);
#pragma unroll
      for (int j = 0; j < 4; j++) {
        uint32_t v = (uint32_t)f2bf(f0[j]) | ((uint32_t)f2bf(f1[j]) << 16);
        *(uint32_t*)&Bs[(ng + j) * 40 + 2 * kp] = v;
      }
    }
    __syncthreads();
    // compute: 4 b-frags + 5 a-frags -> 20 MFMA per wave
    short8 bfr[NTILES];
#pragma unroll
    for (int nt = 0; nt < NTILES; nt++)
      bfr[nt] = *(const short8*)&Bs[(nt * 16 + l15) * 40 + q * 8];
#pragma unroll
    for (int mt = 0; mt < MTILES; mt++) {
      int mrow = (w * MTILES + mt) * 16 + l15;
      short8 afr = *(const short8*)&As[mrow * 32 + q * 8];
#pragma unroll
      for (int nt = 0; nt < NTILES; nt++)
        acc[mt][nt] =
            __builtin_amdgcn_mfma_f32_16x16x32_bf16(afr, bfr[nt], acc[mt][nt], 0, 0, 0);
    }
    __syncthreads();
  }
  // epilogue: partials [S][320][4096]
#pragma unroll
  for (int mt = 0; mt < MTILES; mt++)
#pragma unroll
    for (int nt = 0; nt < NTILES; nt++)
#pragma unroll
      for (int r = 0; r < 4; r++) {
        int m = (w * MTILES + mt) * 16 + q * 4 + r;
        int n = nb * 64 + nt * 16 + l15;
        P[((size_t)s * 320 + m) * 4096 + n] = acc[mt][nt][r];
      }
}

// ---------------------------------------------------------------------------
// 9) reduce split-K partials + bias + relu -> bf16 activations
// ---------------------------------------------------------------------------
__global__ __launch_bounds__(256) void reduce_kernel(
    const float* __restrict__ P, const float* __restrict__ bias,
    uint16_t* __restrict__ X) {
  int i = blockIdx.x * 256 + threadIdx.x;
  if (i >= 320 * 4096) return;
  int n = i & 4095;
  float s = 0.0f;
#pragma unroll
  for (int j = 0; j < 8; j++) s += P[(size_t)j * 320 * 4096 + i];
  s += bias[n];
  s = fmaxf(s, 0.0f);
  X[i] = f2bf(s);
}

// ---------------------------------------------------------------------------
// 10) cls/reg head + softmax + box decode -> out[300][105]
// ---------------------------------------------------------------------------
__global__ __launch_bounds__(512) void head_kernel(
    const uint16_t* __restrict__ X3, const float* __restrict__ cls_w,
    const float* __restrict__ cls_b, const float* __restrict__ reg_w,
    const float* __restrict__ reg_b, const float4* __restrict__ keep_xywh,
    float* __restrict__ out) {
  int m = blockIdx.x;
  int tid = threadIdx.x;
  __shared__ float xr[4096];
  __shared__ float part[4][112];
  __shared__ float row[112];
  const uint16_t* xp = X3 + (size_t)m * 4096;
  for (int i = tid; i < 4096; i += 512) xr[i] = bf2f(xp[i]);
  __syncthreads();
  int qq = tid >> 7, n = tid & 127;
  if (n < 105) {
    float acc = 0.0f;
    int kbeg = qq * 1024;
    if (n < 21) {
      const float* wp = cls_w + n;
      for (int k = kbeg; k < kbeg + 1024; k++) acc += xr[k] * wp[k * 21];
    } else {
      const float* wp = reg_w + (n - 21);
      for (int k = kbeg; k < kbeg + 1024; k++) acc += xr[k] * wp[k * 84];
    }
    part[qq][n] = acc;
  }
  __syncthreads();
  if (tid < 105) {
    float v = part[0][tid] + part[1][tid] + part[2][tid] + part[3][tid];
    if (tid < 21) {
      v += cls_b[tid];
    } else {
      int j = tid - 21;
      v += reg_b[j];
      v *= ((j & 3) < 2) ? 0.1f : 0.2f;
    }
    row[tid] = v;
  }
  __syncthreads();
  if (tid < 105) {
    float val;
    if (tid < 21) {
      float mx = row[0];
      for (int j = 1; j < 21; j++) mx = fmaxf(mx, row[j]);
      float sum = 0.0f;
      for (int j = 0; j < 21; j++) sum += expf(row[j] - mx);
      val = expf(row[tid] - mx) / sum;
    } else {
      int j = tid - 21;
      int comp = j & 3;
      int cls = j >> 2;
      float r0 = row[21 + cls * 4 + 0];
      float r1 = row[21 + cls * 4 + 1];
      float r2 = row[21 + cls * 4 + 2];
      float r3 = row[21 + cls * 4 + 3];
      float4 sb = keep_xywh[m];
      float x = sb.x + r0 * sb.z;
      float y = sb.y + r1 * sb.w;
      if (comp == 0) val = x;
      else if (comp == 1) val = y;
      else if (comp == 2) val = x + sb.z * expf(r2);
      else val = y + sb.w * expf(r3);
      val = fminf(fmaxf(val, 0.0f), 800.0f);
    }
    out[(size_t)m * 105 + tid] = val;
  }
}

// ---------------------------------------------------------------------------
// launch
// ---------------------------------------------------------------------------
extern "C" void kernel_launch(void* const* d_in, const int* in_sizes, int n_in,
                              void* d_out, int out_size, void* d_ws, size_t ws_size,
                              hipStream_t stream) {
  const float* feat      = (const float*)d_in[0];
  const float* proposals = (const float*)d_in[1];
  const float* scores    = (const float*)d_in[2];
  const float* fc1_w     = (const float*)d_in[3];
  const float* fc1_b     = (const float*)d_in[4];
  const float* fc2_w     = (const float*)d_in[5];
  const float* fc2_b     = (const float*)d_in[6];
  const float* cls_w     = (const float*)d_in[7];
  const float* cls_b     = (const float*)d_in[8];
  const float* reg_w     = (const float*)d_in[9];
  const float* reg_b     = (const float*)d_in[10];
  float* out = (float*)d_out;

  char* ws = (char*)d_ws;
  size_t off = 0;
  auto alloc = [&](size_t bytes) -> void* {
    void* p = ws + off;
    off = (off + bytes + 255) & ~(size_t)255;
    return p;
  };
  uint32_t* keys      = (uint32_t*)alloc(22500 * 4);
  int*      misc      = (int*)alloc(256);           // [0]=cutoff, [1]=counter
  uint64_t* sortbuf   = (uint64_t*)alloc(8192 * 8);
  int*      sorted_idx= (int*)alloc(6000 * 4);
  float4*   sxyxy     = (float4*)alloc(6000 * 16);
  float4*   sxywh     = (float4*)alloc(6000 * 16);
  float4*   keep_xyxy = (float4*)alloc(300 * 16);
  float4*   keep_xywh = (float4*)alloc(300 * 16);
  uint16_t* Abuf      = (uint16_t*)alloc((size_t)320 * 25088 * 2);
  uint16_t* X2        = (uint16_t*)alloc((size_t)320 * 4096 * 2);
  uint16_t* X3        = (uint16_t*)alloc((size_t)320 * 4096 * 2);
  float*    partials  = (float*)alloc((size_t)8 * 320 * 4096 * 4);
  uint32_t* cutoff    = (uint32_t*)misc;
  int*      counter   = misc + 1;

  prep_kernel<<<88, 256, 0, stream>>>(proposals, scores, keys, sortbuf, counter);
  select_kernel<<<1, 1024, 0, stream>>>(keys, cutoff);
  compact_kernel<<<88, 256, 0, stream>>>(keys, cutoff, sortbuf, counter);
  sort_kernel<<<1, 1024, 0, stream>>>(sortbuf, sorted_idx);
  gather_kernel<<<24, 256, 0, stream>>>(proposals, sorted_idx, sxyxy, sxywh);
  nms_kernel<<<1, 1024, 0, stream>>>(sxyxy, sxywh, keep_xyxy, keep_xywh);
  roi_kernel<<<320, 256, 0, stream>>>(feat, keep_xyxy, Abuf);
  gemm_kernel<<<dim3(64, 8), 256, 0, stream>>>(Abuf, fc1_w, partials, 25088, 8);
  reduce_kernel<<<5120, 256, 0, stream>>>(partials, fc1_b, X2);
  gemm_kernel<<<dim3(64, 8), 256, 0, stream>>>(X2, fc2_w, partials, 4096, 8);
  reduce_kernel<<<5120, 256, 0, stream>>>(partials, fc2_b, X3);
  head_kernel<<<300, 512, 0, stream>>>(X3, cls_w, cls_b, reg_w, reg_b, keep_xywh, out);
}

// Round 2
// 1216.119 us; speedup vs baseline: 1.3714x; 1.3714x over previous
//
#include <hip/hip_runtime.h>
#include <stdint.h>

// ---------------------------------------------------------------------------
// FasterRCNN head on MI355X.
// Pipeline: mask scores -> radix-select 6000th -> compact -> bitonic sort
//           -> IoU bit-matrix + bitmask greedy NMS (300) -> ROIAlign (bf16)
//           -> fc1/fc2 (bf16 MFMA, split-K, fused fp32->bf16 weight convert)
//           -> cls/reg head -> softmax + decode.
// ---------------------------------------------------------------------------

#define NEGV -1e30f

typedef __attribute__((ext_vector_type(8))) short short8;
typedef __attribute__((ext_vector_type(4))) float f32x4;

__device__ __forceinline__ uint16_t f2bf(float f) {
  uint32_t u = __builtin_bit_cast(uint32_t, f);
  u = (u + 0x7FFFu + ((u >> 16) & 1u)) >> 16;
  return (uint16_t)u;
}
__device__ __forceinline__ float bf2f(uint16_t h) {
  return __builtin_bit_cast(float, ((uint32_t)h) << 16);
}
// monotone float -> uint32 key (order-preserving for all finite floats)
__device__ __forceinline__ uint32_t fkey(float f) {
  uint32_t u = __builtin_bit_cast(uint32_t, f);
  return (u & 0x80000000u) ? ~u : (u | 0x80000000u);
}

// ---------------------------------------------------------------------------
// 1) score mask + key build; also init sort buffer + atomic counter
// ---------------------------------------------------------------------------
__global__ __launch_bounds__(256) void prep_kernel(
    const float* __restrict__ proposals, const float* __restrict__ scores,
    uint32_t* __restrict__ keys, uint64_t* __restrict__ sortbuf,
    int* __restrict__ counter) {
  int i = blockIdx.x * 256 + threadIdx.x;
  if (i < 8192) sortbuf[i] = 0ULL;  // sentinel: below every real entry
  if (i == 0) *counter = 0;
  if (i < 22500) {
    float w = proposals[i * 4 + 2], h = proposals[i * 4 + 3];
    float s = scores[i];
    s = (w < 16.0f || h < 16.0f) ? NEGV : s;
    keys[i] = fkey(s);
  }
}

// ---------------------------------------------------------------------------
// 2) radix select: exact key value of the 6000th largest
// ---------------------------------------------------------------------------
__global__ __launch_bounds__(1024) void select_kernel(
    const uint32_t* __restrict__ keys, uint32_t* __restrict__ cutoff) {
  __shared__ uint32_t hist[256];
  __shared__ uint32_t s_prefix;
  __shared__ int s_remaining;
  int tid = threadIdx.x;
  if (tid == 0) { s_prefix = 0; s_remaining = 6000; }
  __syncthreads();
  for (int round = 0; round < 4; round++) {
    int shift = 24 - round * 8;
    for (int i = tid; i < 256; i += 1024) hist[i] = 0;
    __syncthreads();
    uint32_t prefix = s_prefix;
    uint32_t pmask = (round == 0) ? 0u : (0xFFFFFFFFu << (shift + 8));
    for (int i = tid; i < 22500; i += 1024) {
      uint32_t kv = keys[i];
      if ((kv & pmask) == (prefix & pmask))
        atomicAdd(&hist[(kv >> shift) & 255u], 1u);
    }
    __syncthreads();
    if (tid == 0) {
      int rem = s_remaining;
      int chosen = 0;
      for (int b = 255; b >= 0; b--) {
        int c = (int)hist[b];
        if (c >= rem) { chosen = b; break; }
        rem -= c;
      }
      s_prefix = prefix | ((uint32_t)chosen << shift);
      s_remaining = rem;
    }
    __syncthreads();
  }
  if (tid == 0) *cutoff = s_prefix;
}

// ---------------------------------------------------------------------------
// 3) compact all entries with key >= cutoff  (6000 + a few ties at most)
// ---------------------------------------------------------------------------
__global__ __launch_bounds__(256) void compact_kernel(
    const uint32_t* __restrict__ keys, const uint32_t* __restrict__ cutoff,
    uint64_t* __restrict__ sortbuf, int* __restrict__ counter) {
  int i = blockIdx.x * 256 + threadIdx.x;
  if (i >= 22500) return;
  uint32_t kv = keys[i];
  if (kv >= *cutoff) {
    int p = atomicAdd(counter, 1);
    if (p < 8192)
      sortbuf[p] = ((uint64_t)kv << 32) | (uint32_t)(~(uint32_t)i);
  }
}

// ---------------------------------------------------------------------------
// 4) single-block bitonic sort of 8192 (desc by score, asc by index) -> top6000
// ---------------------------------------------------------------------------
__global__ __launch_bounds__(1024) void sort_kernel(
    const uint64_t* __restrict__ sortbuf, int* __restrict__ sorted_idx) {
  __shared__ uint64_t v[8192];
  int tid = threadIdx.x;
  for (int i = tid; i < 8192; i += 1024) v[i] = sortbuf[i];
  __syncthreads();
  for (int k = 2; k <= 8192; k <<= 1) {
    for (int j = k >> 1; j > 0; j >>= 1) {
      for (int i = tid; i < 8192; i += 1024) {
        int ixj = i ^ j;
        if (ixj > i) {
          uint64_t a = v[i], b = v[ixj];
          bool up = (i & k) == 0;  // descending overall
          if (up ? (a < b) : (a > b)) { v[i] = b; v[ixj] = a; }
        }
      }
      __syncthreads();
    }
  }
  for (int i = tid; i < 6000; i += 1024)
    sorted_idx[i] = (int)(~(uint32_t)(v[i] & 0xFFFFFFFFull));
}

// ---------------------------------------------------------------------------
// 5) gather sorted boxes: xywh + xyxy
// ---------------------------------------------------------------------------
__global__ __launch_bounds__(256) void gather_kernel(
    const float* __restrict__ proposals, const int* __restrict__ sorted_idx,
    float4* __restrict__ sxyxy, float4* __restrict__ sxywh) {
  int i = blockIdx.x * 256 + threadIdx.x;
  if (i >= 6000) return;
  int oi = sorted_idx[i];
  float x = proposals[oi * 4 + 0], y = proposals[oi * 4 + 1];
  float w = proposals[oi * 4 + 2], h = proposals[oi * 4 + 3];
  sxywh[i] = make_float4(x, y, w, h);
  sxyxy[i] = make_float4(x, y, x + w, y + h);  // single adds: exact vs ref
}

// ---------------------------------------------------------------------------
// 6a) IoU suppression bit-matrix: M[j][w] bit b = IoU(box j, box w*32+b) > 0.7
//     row box area first in the denominator (matches ref op order exactly).
// ---------------------------------------------------------------------------
__global__ __launch_bounds__(256) void ioumat_kernel(
    const float4* __restrict__ boxes, uint32_t* __restrict__ M) {
#pragma clang fp contract(off)
  int idx = blockIdx.x * 256 + threadIdx.x;  // j*188 + w
  if (idx >= 6000 * 188) return;
  int j = idx / 188;
  int w = idx - j * 188;
  float4 bb = boxes[j];
  float ba = (bb.z - bb.x) * (bb.w - bb.y);
  int base = w * 32;
  int lim = min(6000 - base, 32);
  uint32_t bits = 0;
  for (int b = 0; b < lim; b++) {
    float4 ob = boxes[base + b];
    float xx1 = fmaxf(bb.x, ob.x);
    float yy1 = fmaxf(bb.y, ob.y);
    float xx2 = fminf(bb.z, ob.z);
    float yy2 = fminf(bb.w, ob.w);
    float inter = fmaxf(xx2 - xx1, 0.0f) * fmaxf(yy2 - yy1, 0.0f);
    float oa = (ob.z - ob.x) * (ob.w - ob.y);
    float iou = inter / (ba + oa - inter + 1e-9f);
    if (iou > 0.7f) bits |= (1u << b);
  }
  M[idx] = bits;
}

// ---------------------------------------------------------------------------
// 6b) bitmask greedy reduce: chunks of 64, register-only intra-chunk scan,
//     parallel OR of kept rows into remv. Exactly reference-greedy order.
// ---------------------------------------------------------------------------
__global__ __launch_bounds__(256) void nms_reduce_kernel(
    const uint32_t* __restrict__ M, const float4* __restrict__ sxyxy,
    const float4* __restrict__ sxywh, float4* __restrict__ keep_xyxy,
    float4* __restrict__ keep_xywh) {
  __shared__ uint32_t remv[188];
  __shared__ int keeps[300];
  __shared__ int s_ck[64];
  __shared__ int s_nk, s_nck;
  int tid = threadIdx.x;
  if (tid < 188) remv[tid] = (tid == 187) ? 0xFFFF0000u : 0u;  // bits>=6000 off
  if (tid == 0) { s_nk = 0; s_nck = 0; }
  __syncthreads();
  for (int c = 0; c < 94; c++) {
    if (tid < 64) {
      int row = c * 64 + tid;
      uint32_t lo = 0, hi = 0;
      if (row < 6000) {
        lo = M[(size_t)row * 188 + 2 * c];
        hi = M[(size_t)row * 188 + 2 * c + 1];
      }
      uint64_t alive =
          ~(((uint64_t)remv[2 * c + 1] << 32) | (uint64_t)remv[2 * c]);
      int nk = s_nk;
      int nck = 0;
      while (alive != 0 && nk < 300) {
        int b = (int)__builtin_ctzll(alive);
        int j = c * 64 + b;
        if (tid == 0) { keeps[nk] = j; s_ck[nck] = j; }
        nk++;
        nck++;
        uint64_t rb = ((uint64_t)(uint32_t)__shfl((int)hi, b, 64) << 32) |
                      (uint64_t)(uint32_t)__shfl((int)lo, b, 64);
        alive &= ~rb;
        alive &= ~(1ull << b);  // self (rb should contain it; belt+braces)
      }
      if (tid == 0) { s_nk = nk; s_nck = nck; }
    }
    __syncthreads();
    int nck = s_nck;
    for (int kk = 0; kk < nck; kk++) {
      int j = s_ck[kk];
      if (tid < 188) remv[tid] |= M[(size_t)j * 188 + tid];
    }
    __syncthreads();
    if (s_nk >= 300) break;
  }
  __syncthreads();
  int nk = s_nk;
  for (int i = tid; i < 300; i += 256) {
    int kp = (i < nk) ? keeps[i] : 0;  // ref argmax-over-all-NEG fallback
    keep_xyxy[i] = sxyxy[kp];
    keep_xywh[i] = sxywh[kp];
  }
}

// ---------------------------------------------------------------------------
// 7) ROIAlign -> A matrix bf16 [320][25088]  (rows 300..319 zero pad)
//    k = c*49 + py*7 + px  (matches reshape order)
// ---------------------------------------------------------------------------
__global__ __launch_bounds__(256) void roi_kernel(
    const float* __restrict__ feat, const float4* __restrict__ keep_xyxy,
    uint16_t* __restrict__ A) {
  int r = blockIdx.x;
  int tid = threadIdx.x;
  uint16_t* out = A + (size_t)r * 25088;
  if (r >= 300) {
    for (int k = tid; k < 25088; k += 256) out[k] = 0;
    return;
  }
  __shared__ int xi0[14], xi1[14], yi0[14], yi1[14];
  __shared__ float wxs[14], wys[14];
  if (tid < 28) {
    int axis = tid / 14;  // 0 = x, 1 = y
    int t = tid % 14;
    int g = t >> 1, sxi = t & 1;
    float4 box = keep_xyxy[r];
    float lo = (axis ? box.y : box.x) * 0.0625f;
    float hi = (axis ? box.w : box.z) * 0.0625f;
    float bsz = (hi - lo) / 7.0f;
    float sub = ((float)sxi + 0.5f) * 0.5f;  // 0.25 / 0.75 exact
    float coord = lo + ((float)g + sub) * bsz;
    float f = floorf(coord);
    float frac = coord - f;
    int i0 = (int)f;
    i0 = min(max(i0, 0), 49);
    int i1 = min(i0 + 1, 49);
    if (axis == 0) { xi0[t] = i0; xi1[t] = i1; wxs[t] = frac; }
    else           { yi0[t] = i0; yi1[t] = i1; wys[t] = frac; }
  }
  __syncthreads();
  for (int k = tid; k < 25088; k += 256) {
    int c = k / 49;
    int pos = k - c * 49;
    int py = pos / 7, px = pos - py * 7;
    const float* fc = feat + (size_t)c * 2500;
    float val = 0.0f;
#pragma unroll
    for (int sy = 0; sy < 2; sy++) {
      int iy = py * 2 + sy;
      float wy = wys[iy];
      int y0 = yi0[iy], y1 = yi1[iy];
#pragma unroll
      for (int sx = 0; sx < 2; sx++) {
        int ix = px * 2 + sx;
        float wx = wxs[ix];
        int x0 = xi0[ix], x1 = xi1[ix];
        float v00 = fc[y0 * 50 + x0], v01 = fc[y0 * 50 + x1];
        float v10 = fc[y1 * 50 + x0], v11 = fc[y1 * 50 + x1];
        val += v00 * (1.0f - wy) * (1.0f - wx) + v01 * (1.0f - wy) * wx +
               v10 * wy * (1.0f - wx) + v11 * wy * wx;
      }
    }
    out[k] = f2bf(val * 0.25f);
  }
}

// ---------------------------------------------------------------------------
// 8) split-K bf16 MFMA GEMM:  P[s] += A[320,K_chunk] * W[K_chunk, 4096-col64]
// ---------------------------------------------------------------------------
#define MTILES 5
#define NTILES 4
__global__ __launch_bounds__(256) void gemm_kernel(
    const uint16_t* __restrict__ A, const float* __restrict__ W,
    float* __restrict__ P, int K, int S) {
  __shared__ uint16_t As[320 * 32];  // packed [m][32], 64B rows
  __shared__ uint16_t Bs[64 * 40];   // [n][k] 80B rows (32 used + 8 pad)
  const int nb = blockIdx.x;
  const int s = blockIdx.y;
  const int kchunk = K / S;
  const int steps = kchunk >> 5;
  const int k0base = s * kchunk;
  const int tid = threadIdx.x;
  const int w = tid >> 6;
  const int l = tid & 63;
  const int q = l >> 4;
  const int l15 = l & 15;

  f32x4 acc[MTILES][NTILES];
#pragma unroll
  for (int i = 0; i < MTILES; i++)
#pragma unroll
    for (int j = 0; j < NTILES; j++) acc[i][j] = (f32x4)0.0f;

  const int ng = (tid & 15) << 2;  // n group of 4 for B staging
  const int kp = tid >> 4;         // k-pair 0..15

  for (int kk = 0; kk < steps; kk++) {
    const int k0 = k0base + (kk << 5);
#pragma unroll
    for (int t = 0; t < 5; t++) {
      int cidx = w * 320 + t * 64 + l;  // 16B chunk id
      int m = cidx >> 2;
      int co = (cidx & 3) << 3;         // ushort offset in row
      const uint16_t* gp = A + (size_t)m * K + k0 + co;
      __builtin_amdgcn_global_load_lds(
          (const __attribute__((address_space(1))) void*)gp,
          (__attribute__((address_space(3))) void*)(As + (w * 320 + t * 64) * 8),
          16, 0, 0);
    }
    {
      const float* wp = W + (size_t)(k0 + 2 * kp) * 4096 + nb * 64 + ng;
      f32x4 f0 = *(const f32x4*)wp;
      f32x4 f1 = *(const f32x4*)(wp + 4096);
#pragma unroll
      for (int j = 0; j < 4; j++) {
        uint32_t v = (uint32_t)f2bf(f0[j]) | ((uint32_t)f2bf(f1[j]) << 16);
        *(uint32_t*)&Bs[(ng + j) * 40 + 2 * kp] = v;
      }
    }
    __syncthreads();
    short8 bfr[NTILES];
#pragma unroll
    for (int nt = 0; nt < NTILES; nt++)
      bfr[nt] = *(const short8*)&Bs[(nt * 16 + l15) * 40 + q * 8];
#pragma unroll
    for (int mt = 0; mt < MTILES; mt++) {
      int mrow = (w * MTILES + mt) * 16 + l15;
      short8 afr = *(const short8*)&As[mrow * 32 + q * 8];
#pragma unroll
      for (int nt = 0; nt < NTILES; nt++)
        acc[mt][nt] =
            __builtin_amdgcn_mfma_f32_16x16x32_bf16(afr, bfr[nt], acc[mt][nt], 0, 0, 0);
    }
    __syncthreads();
  }
#pragma unroll
  for (int mt = 0; mt < MTILES; mt++)
#pragma unroll
    for (int nt = 0; nt < NTILES; nt++)
#pragma unroll
      for (int r = 0; r < 4; r++) {
        int m = (w * MTILES + mt) * 16 + q * 4 + r;
        int n = nb * 64 + nt * 16 + l15;
        P[((size_t)s * 320 + m) * 4096 + n] = acc[mt][nt][r];
      }
}

// ---------------------------------------------------------------------------
// 9) reduce split-K partials + bias + relu -> bf16 activations
// ---------------------------------------------------------------------------
__global__ __launch_bounds__(256) void reduce_kernel(
    const float* __restrict__ P, const float* __restrict__ bias,
    uint16_t* __restrict__ X) {
  int i = blockIdx.x * 256 + threadIdx.x;
  if (i >= 320 * 4096) return;
  int n = i & 4095;
  float s = 0.0f;
#pragma unroll
  for (int j = 0; j < 8; j++) s += P[(size_t)j * 320 * 4096 + i];
  s += bias[n];
  s = fmaxf(s, 0.0f);
  X[i] = f2bf(s);
}

// ---------------------------------------------------------------------------
// 10) cls/reg head + softmax + box decode -> out[300][105]
// ---------------------------------------------------------------------------
__global__ __launch_bounds__(512) void head_kernel(
    const uint16_t* __restrict__ X3, const float* __restrict__ cls_w,
    const float* __restrict__ cls_b, const float* __restrict__ reg_w,
    const float* __restrict__ reg_b, const float4* __restrict__ keep_xywh,
    float* __restrict__ out) {
  int m = blockIdx.x;
  int tid = threadIdx.x;
  __shared__ float xr[4096];
  __shared__ float part[4][112];
  __shared__ float row[112];
  const uint16_t* xp = X3 + (size_t)m * 4096;
  for (int i = tid; i < 4096; i += 512) xr[i] = bf2f(xp[i]);
  __syncthreads();
  int qq = tid >> 7, n = tid & 127;
  if (n < 105) {
    float acc = 0.0f;
    int kbeg = qq * 1024;
    if (n < 21) {
      const float* wp = cls_w + n;
      for (int k = kbeg; k < kbeg + 1024; k++) acc += xr[k] * wp[k * 21];
    } else {
      const float* wp = reg_w + (n - 21);
      for (int k = kbeg; k < kbeg + 1024; k++) acc += xr[k] * wp[k * 84];
    }
    part[qq][n] = acc;
  }
  __syncthreads();
  if (tid < 105) {
    float v = part[0][tid] + part[1][tid] + part[2][tid] + part[3][tid];
    if (tid < 21) {
      v += cls_b[tid];
    } else {
      int j = tid - 21;
      v += reg_b[j];
      v *= ((j & 3) < 2) ? 0.1f : 0.2f;
    }
    row[tid] = v;
  }
  __syncthreads();
  if (tid < 105) {
    float val;
    if (tid < 21) {
      float mx = row[0];
      for (int j = 1; j < 21; j++) mx = fmaxf(mx, row[j]);
      float sum = 0.0f;
      for (int j = 0; j < 21; j++) sum += expf(row[j] - mx);
      val = expf(row[tid] - mx) / sum;
    } else {
      int j = tid - 21;
      int comp = j & 3;
      int cls = j >> 2;
      float r0 = row[21 + cls * 4 + 0];
      float r1 = row[21 + cls * 4 + 1];
      float r2 = row[21 + cls * 4 + 2];
      float r3 = row[21 + cls * 4 + 3];
      float4 sb = keep_xywh[m];
      float x = sb.x + r0 * sb.z;
      float y = sb.y + r1 * sb.w;
      if (comp == 0) val = x;
      else if (comp == 1) val = y;
      else if (comp == 2) val = x + sb.z * expf(r2);
      else val = y + sb.w * expf(r3);
      val = fminf(fmaxf(val, 0.0f), 800.0f);
    }
    out[(size_t)m * 105 + tid] = val;
  }
}

// ---------------------------------------------------------------------------
// launch
// ---------------------------------------------------------------------------
extern "C" void kernel_launch(void* const* d_in, const int* in_sizes, int n_in,
                              void* d_out, int out_size, void* d_ws, size_t ws_size,
                              hipStream_t stream) {
  const float* feat      = (const float*)d_in[0];
  const float* proposals = (const float*)d_in[1];
  const float* scores    = (const float*)d_in[2];
  const float* fc1_w     = (const float*)d_in[3];
  const float* fc1_b     = (const float*)d_in[4];
  const float* fc2_w     = (const float*)d_in[5];
  const float* fc2_b     = (const float*)d_in[6];
  const float* cls_w     = (const float*)d_in[7];
  const float* cls_b     = (const float*)d_in[8];
  const float* reg_w     = (const float*)d_in[9];
  const float* reg_b     = (const float*)d_in[10];
  float* out = (float*)d_out;

  char* ws = (char*)d_ws;
  size_t off = 0;
  auto alloc = [&](size_t bytes) -> void* {
    void* p = ws + off;
    off = (off + bytes + 255) & ~(size_t)255;
    return p;
  };
  uint32_t* keys      = (uint32_t*)alloc(22500 * 4);
  int*      misc      = (int*)alloc(256);           // [0]=cutoff, [1]=counter
  uint64_t* sortbuf   = (uint64_t*)alloc(8192 * 8);
  int*      sorted_idx= (int*)alloc(6000 * 4);
  float4*   sxyxy     = (float4*)alloc(6000 * 16);
  float4*   sxywh     = (float4*)alloc(6000 * 16);
  float4*   keep_xyxy = (float4*)alloc(300 * 16);
  float4*   keep_xywh = (float4*)alloc(300 * 16);
  uint16_t* Abuf      = (uint16_t*)alloc((size_t)320 * 25088 * 2);
  uint16_t* X2        = (uint16_t*)alloc((size_t)320 * 4096 * 2);
  uint16_t* X3        = (uint16_t*)alloc((size_t)320 * 4096 * 2);
  float*    partials  = (float*)alloc((size_t)8 * 320 * 4096 * 4);
  uint32_t* cutoff    = (uint32_t*)misc;
  int*      counter   = misc + 1;
  // IoU bit-matrix (4.5 MB) aliases the split-K partials buffer: M is dead
  // before the first gemm_kernel writes partials (same stream, sequential).
  uint32_t* M = (uint32_t*)partials;

  prep_kernel<<<88, 256, 0, stream>>>(proposals, scores, keys, sortbuf, counter);
  select_kernel<<<1, 1024, 0, stream>>>(keys, cutoff);
  compact_kernel<<<88, 256, 0, stream>>>(keys, cutoff, sortbuf, counter);
  sort_kernel<<<1, 1024, 0, stream>>>(sortbuf, sorted_idx);
  gather_kernel<<<24, 256, 0, stream>>>(proposals, sorted_idx, sxyxy, sxywh);
  ioumat_kernel<<<4407, 256, 0, stream>>>(sxyxy, M);
  nms_reduce_kernel<<<1, 256, 0, stream>>>(M, sxyxy, sxywh, keep_xyxy, keep_xywh);
  roi_kernel<<<320, 256, 0, stream>>>(feat, keep_xyxy, Abuf);
  gemm_kernel<<<dim3(64, 8), 256, 0, stream>>>(Abuf, fc1_w, partials, 25088, 8);
  reduce_kernel<<<5120, 256, 0, stream>>>(partials, fc1_b, X2);
  gemm_kernel<<<dim3(64, 8), 256, 0, stream>>>(X2, fc2_w, partials, 4096, 8);
  reduce_kernel<<<5120, 256, 0, stream>>>(partials, fc2_b, X3);
  head_kernel<<<300, 512, 0, stream>>>(X3, cls_w, cls_b, reg_w, reg_b, keep_xywh, out);
}

// Round 3
// 1215.949 us; speedup vs baseline: 1.3716x; 1.0001x over previous
//
#include <hip/hip_runtime.h>
#include <stdint.h>

// ---------------------------------------------------------------------------
// FasterRCNN head on MI355X.
// Pipeline: mask scores -> radix-select 6000th -> compact -> bitonic sort
//           -> IoU bit-matrix + bitmask greedy NMS (300) -> ROIAlign (bf16)
//           -> fc1/fc2 (bf16 MFMA, split-K, fused fp32->bf16 weight convert)
//           -> head GEMM (MFMA, no-LDS) -> softmax + decode epilogue.
// ---------------------------------------------------------------------------

#define NEGV -1e30f

typedef __attribute__((ext_vector_type(8))) short short8;
typedef __attribute__((ext_vector_type(4))) float f32x4;

__device__ __forceinline__ uint16_t f2bf(float f) {
  uint32_t u = __builtin_bit_cast(uint32_t, f);
  u = (u + 0x7FFFu + ((u >> 16) & 1u)) >> 16;
  return (uint16_t)u;
}
__device__ __forceinline__ float bf2f(uint16_t h) {
  return __builtin_bit_cast(float, ((uint32_t)h) << 16);
}
// monotone float -> uint32 key (order-preserving for all finite floats)
__device__ __forceinline__ uint32_t fkey(float f) {
  uint32_t u = __builtin_bit_cast(uint32_t, f);
  return (u & 0x80000000u) ? ~u : (u | 0x80000000u);
}

// ---------------------------------------------------------------------------
// 1) score mask + key build; also init sort buffer + atomic counter
// ---------------------------------------------------------------------------
__global__ __launch_bounds__(256) void prep_kernel(
    const float* __restrict__ proposals, const float* __restrict__ scores,
    uint32_t* __restrict__ keys, uint64_t* __restrict__ sortbuf,
    int* __restrict__ counter) {
  int i = blockIdx.x * 256 + threadIdx.x;
  if (i < 8192) sortbuf[i] = 0ULL;  // sentinel: below every real entry
  if (i == 0) *counter = 0;
  if (i < 22500) {
    float w = proposals[i * 4 + 2], h = proposals[i * 4 + 3];
    float s = scores[i];
    s = (w < 16.0f || h < 16.0f) ? NEGV : s;
    keys[i] = fkey(s);
  }
}

// ---------------------------------------------------------------------------
// 2) radix select: exact key value of the 6000th largest
// ---------------------------------------------------------------------------
__global__ __launch_bounds__(1024) void select_kernel(
    const uint32_t* __restrict__ keys, uint32_t* __restrict__ cutoff) {
  __shared__ uint32_t hist[256];
  __shared__ uint32_t s_prefix;
  __shared__ int s_remaining;
  int tid = threadIdx.x;
  if (tid == 0) { s_prefix = 0; s_remaining = 6000; }
  __syncthreads();
  for (int round = 0; round < 4; round++) {
    int shift = 24 - round * 8;
    for (int i = tid; i < 256; i += 1024) hist[i] = 0;
    __syncthreads();
    uint32_t prefix = s_prefix;
    uint32_t pmask = (round == 0) ? 0u : (0xFFFFFFFFu << (shift + 8));
    for (int i = tid; i < 22500; i += 1024) {
      uint32_t kv = keys[i];
      if ((kv & pmask) == (prefix & pmask))
        atomicAdd(&hist[(kv >> shift) & 255u], 1u);
    }
    __syncthreads();
    if (tid == 0) {
      int rem = s_remaining;
      int chosen = 0;
      for (int b = 255; b >= 0; b--) {
        int c = (int)hist[b];
        if (c >= rem) { chosen = b; break; }
        rem -= c;
      }
      s_prefix = prefix | ((uint32_t)chosen << shift);
      s_remaining = rem;
    }
    __syncthreads();
  }
  if (tid == 0) *cutoff = s_prefix;
}

// ---------------------------------------------------------------------------
// 3) compact all entries with key >= cutoff  (6000 + a few ties at most)
// ---------------------------------------------------------------------------
__global__ __launch_bounds__(256) void compact_kernel(
    const uint32_t* __restrict__ keys, const uint32_t* __restrict__ cutoff,
    uint64_t* __restrict__ sortbuf, int* __restrict__ counter) {
  int i = blockIdx.x * 256 + threadIdx.x;
  if (i >= 22500) return;
  uint32_t kv = keys[i];
  if (kv >= *cutoff) {
    int p = atomicAdd(counter, 1);
    if (p < 8192)
      sortbuf[p] = ((uint64_t)kv << 32) | (uint32_t)(~(uint32_t)i);
  }
}

// ---------------------------------------------------------------------------
// 4) single-block bitonic sort of 8192 (desc by score, asc by index) -> top6000
// ---------------------------------------------------------------------------
__global__ __launch_bounds__(1024) void sort_kernel(
    const uint64_t* __restrict__ sortbuf, int* __restrict__ sorted_idx) {
  __shared__ uint64_t v[8192];
  int tid = threadIdx.x;
  for (int i = tid; i < 8192; i += 1024) v[i] = sortbuf[i];
  __syncthreads();
  for (int k = 2; k <= 8192; k <<= 1) {
    for (int j = k >> 1; j > 0; j >>= 1) {
      for (int i = tid; i < 8192; i += 1024) {
        int ixj = i ^ j;
        if (ixj > i) {
          uint64_t a = v[i], b = v[ixj];
          bool up = (i & k) == 0;  // descending overall
          if (up ? (a < b) : (a > b)) { v[i] = b; v[ixj] = a; }
        }
      }
      __syncthreads();
    }
  }
  for (int i = tid; i < 6000; i += 1024)
    sorted_idx[i] = (int)(~(uint32_t)(v[i] & 0xFFFFFFFFull));
}

// ---------------------------------------------------------------------------
// 5) gather sorted boxes: xywh + xyxy
// ---------------------------------------------------------------------------
__global__ __launch_bounds__(256) void gather_kernel(
    const float* __restrict__ proposals, const int* __restrict__ sorted_idx,
    float4* __restrict__ sxyxy, float4* __restrict__ sxywh) {
  int i = blockIdx.x * 256 + threadIdx.x;
  if (i >= 6000) return;
  int oi = sorted_idx[i];
  float x = proposals[oi * 4 + 0], y = proposals[oi * 4 + 1];
  float w = proposals[oi * 4 + 2], h = proposals[oi * 4 + 3];
  sxywh[i] = make_float4(x, y, w, h);
  sxyxy[i] = make_float4(x, y, x + w, y + h);  // single adds: exact vs ref
}

// ---------------------------------------------------------------------------
// 6a) IoU suppression bit-matrix: M[j][w] bit b = IoU(box j, box w*32+b) > 0.7
// ---------------------------------------------------------------------------
__global__ __launch_bounds__(256) void ioumat_kernel(
    const float4* __restrict__ boxes, uint32_t* __restrict__ M) {
#pragma clang fp contract(off)
  int idx = blockIdx.x * 256 + threadIdx.x;  // j*188 + w
  if (idx >= 6000 * 188) return;
  int j = idx / 188;
  int w = idx - j * 188;
  float4 bb = boxes[j];
  float ba = (bb.z - bb.x) * (bb.w - bb.y);
  int base = w * 32;
  int lim = min(6000 - base, 32);
  uint32_t bits = 0;
  for (int b = 0; b < lim; b++) {
    float4 ob = boxes[base + b];
    float xx1 = fmaxf(bb.x, ob.x);
    float yy1 = fmaxf(bb.y, ob.y);
    float xx2 = fminf(bb.z, ob.z);
    float yy2 = fminf(bb.w, ob.w);
    float inter = fmaxf(xx2 - xx1, 0.0f) * fmaxf(yy2 - yy1, 0.0f);
    float oa = (ob.z - ob.x) * (ob.w - ob.y);
    float iou = inter / (ba + oa - inter + 1e-9f);
    if (iou > 0.7f) bits |= (1u << b);
  }
  M[idx] = bits;
}

// ---------------------------------------------------------------------------
// 6b) bitmask greedy reduce: chunks of 64, register-only intra-chunk scan,
//     PARALLEL atomicOr of kept rows into remv (one latency round per chunk).
// ---------------------------------------------------------------------------
__global__ __launch_bounds__(256) void nms_reduce_kernel(
    const uint32_t* __restrict__ M, const float4* __restrict__ sxyxy,
    const float4* __restrict__ sxywh, float4* __restrict__ keep_xyxy,
    float4* __restrict__ keep_xywh) {
  __shared__ uint32_t remv[188];
  __shared__ int keeps[300];
  __shared__ int s_ck[64];
  __shared__ int s_nk, s_nck;
  int tid = threadIdx.x;
  if (tid < 188) remv[tid] = (tid == 187) ? 0xFFFF0000u : 0u;  // bits>=6000 off
  if (tid == 0) { s_nk = 0; s_nck = 0; }
  __syncthreads();
  for (int c = 0; c < 94; c++) {
    if (tid < 64) {
      int row = c * 64 + tid;
      uint32_t lo = 0, hi = 0;
      if (row < 6000) {
        lo = M[(size_t)row * 188 + 2 * c];
        hi = M[(size_t)row * 188 + 2 * c + 1];
      }
      uint64_t alive =
          ~(((uint64_t)remv[2 * c + 1] << 32) | (uint64_t)remv[2 * c]);
      int nk = s_nk;
      int nck = 0;
      while (alive != 0 && nk < 300) {
        int b = (int)__builtin_ctzll(alive);
        int j = c * 64 + b;
        if (tid == 0) { keeps[nk] = j; s_ck[nck] = j; }
        nk++;
        nck++;
        uint64_t rb = ((uint64_t)(uint32_t)__shfl((int)hi, b, 64) << 32) |
                      (uint64_t)(uint32_t)__shfl((int)lo, b, 64);
        alive &= ~rb;
        alive &= ~(1ull << b);  // self (rb should contain it; belt+braces)
      }
      if (tid == 0) { s_nk = nk; s_nck = nck; }
    }
    __syncthreads();
    int nck = s_nck;
    // parallel OR: all kept rows x 188 words at once (loads overlap)
    for (int i = tid; i < nck * 188; i += 256) {
      int r = i / 188;
      int wd = i - r * 188;
      atomicOr(&remv[wd], M[(size_t)s_ck[r] * 188 + wd]);
    }
    __syncthreads();
    if (s_nk >= 300) break;
  }
  __syncthreads();
  int nk = s_nk;
  for (int i = tid; i < 300; i += 256) {
    int kp = (i < nk) ? keeps[i] : 0;  // ref argmax-over-all-NEG fallback
    keep_xyxy[i] = sxyxy[kp];
    keep_xywh[i] = sxywh[kp];
  }
}

// ---------------------------------------------------------------------------
// 7) ROIAlign -> A matrix bf16 [320][25088]  (rows 300..319 zero pad)
// ---------------------------------------------------------------------------
__global__ __launch_bounds__(256) void roi_kernel(
    const float* __restrict__ feat, const float4* __restrict__ keep_xyxy,
    uint16_t* __restrict__ A) {
  int r = blockIdx.x;
  int tid = threadIdx.x;
  uint16_t* out = A + (size_t)r * 25088;
  if (r >= 300) {
    for (int k = tid; k < 25088; k += 256) out[k] = 0;
    return;
  }
  __shared__ int xi0[14], xi1[14], yi0[14], yi1[14];
  __shared__ float wxs[14], wys[14];
  if (tid < 28) {
    int axis = tid / 14;  // 0 = x, 1 = y
    int t = tid % 14;
    int g = t >> 1, sxi = t & 1;
    float4 box = keep_xyxy[r];
    float lo = (axis ? box.y : box.x) * 0.0625f;
    float hi = (axis ? box.w : box.z) * 0.0625f;
    float bsz = (hi - lo) / 7.0f;
    float sub = ((float)sxi + 0.5f) * 0.5f;  // 0.25 / 0.75 exact
    float coord = lo + ((float)g + sub) * bsz;
    float f = floorf(coord);
    float frac = coord - f;
    int i0 = (int)f;
    i0 = min(max(i0, 0), 49);
    int i1 = min(i0 + 1, 49);
    if (axis == 0) { xi0[t] = i0; xi1[t] = i1; wxs[t] = frac; }
    else           { yi0[t] = i0; yi1[t] = i1; wys[t] = frac; }
  }
  __syncthreads();
  for (int k = tid; k < 25088; k += 256) {
    int c = k / 49;
    int pos = k - c * 49;
    int py = pos / 7, px = pos - py * 7;
    const float* fc = feat + (size_t)c * 2500;
    float val = 0.0f;
#pragma unroll
    for (int sy = 0; sy < 2; sy++) {
      int iy = py * 2 + sy;
      float wy = wys[iy];
      int y0 = yi0[iy], y1 = yi1[iy];
#pragma unroll
      for (int sx = 0; sx < 2; sx++) {
        int ix = px * 2 + sx;
        float wx = wxs[ix];
        int x0 = xi0[ix], x1 = xi1[ix];
        float v00 = fc[y0 * 50 + x0], v01 = fc[y0 * 50 + x1];
        float v10 = fc[y1 * 50 + x0], v11 = fc[y1 * 50 + x1];
        val += v00 * (1.0f - wy) * (1.0f - wx) + v01 * (1.0f - wy) * wx +
               v10 * wy * (1.0f - wx) + v11 * wy * wx;
      }
    }
    out[k] = f2bf(val * 0.25f);
  }
}

// ---------------------------------------------------------------------------
// 8) split-K bf16 MFMA GEMM:  P[s] += A[320,K_chunk] * W[K_chunk, 4096-col64]
// ---------------------------------------------------------------------------
#define MTILES 5
#define NTILES 4
__global__ __launch_bounds__(256) void gemm_kernel(
    const uint16_t* __restrict__ A, const float* __restrict__ W,
    float* __restrict__ P, int K, int S) {
  __shared__ uint16_t As[320 * 32];  // packed [m][32], 64B rows
  __shared__ uint16_t Bs[64 * 40];   // [n][k] 80B rows (32 used + 8 pad)
  const int nb = blockIdx.x;
  const int s = blockIdx.y;
  const int kchunk = K / S;
  const int steps = kchunk >> 5;
  const int k0base = s * kchunk;
  const int tid = threadIdx.x;
  const int w = tid >> 6;
  const int l = tid & 63;
  const int q = l >> 4;
  const int l15 = l & 15;

  f32x4 acc[MTILES][NTILES];
#pragma unroll
  for (int i = 0; i < MTILES; i++)
#pragma unroll
    for (int j = 0; j < NTILES; j++) acc[i][j] = (f32x4)0.0f;

  const int ng = (tid & 15) << 2;  // n group of 4 for B staging
  const int kp = tid >> 4;         // k-pair 0..15

  for (int kk = 0; kk < steps; kk++) {
    const int k0 = k0base + (kk << 5);
#pragma unroll
    for (int t = 0; t < 5; t++) {
      int cidx = w * 320 + t * 64 + l;  // 16B chunk id
      int m = cidx >> 2;
      int co = (cidx & 3) << 3;         // ushort offset in row
      const uint16_t* gp = A + (size_t)m * K + k0 + co;
      __builtin_amdgcn_global_load_lds(
          (const __attribute__((address_space(1))) void*)gp,
          (__attribute__((address_space(3))) void*)(As + (w * 320 + t * 64) * 8),
          16, 0, 0);
    }
    {
      const float* wp = W + (size_t)(k0 + 2 * kp) * 4096 + nb * 64 + ng;
      f32x4 f0 = *(const f32x4*)wp;
      f32x4 f1 = *(const f32x4*)(wp + 4096);
#pragma unroll
      for (int j = 0; j < 4; j++) {
        uint32_t v = (uint32_t)f2bf(f0[j]) | ((uint32_t)f2bf(f1[j]) << 16);
        *(uint32_t*)&Bs[(ng + j) * 40 + 2 * kp] = v;
      }
    }
    __syncthreads();
    short8 bfr[NTILES];
#pragma unroll
    for (int nt = 0; nt < NTILES; nt++)
      bfr[nt] = *(const short8*)&Bs[(nt * 16 + l15) * 40 + q * 8];
#pragma unroll
    for (int mt = 0; mt < MTILES; mt++) {
      int mrow = (w * MTILES + mt) * 16 + l15;
      short8 afr = *(const short8*)&As[mrow * 32 + q * 8];
#pragma unroll
      for (int nt = 0; nt < NTILES; nt++)
        acc[mt][nt] =
            __builtin_amdgcn_mfma_f32_16x16x32_bf16(afr, bfr[nt], acc[mt][nt], 0, 0, 0);
    }
    __syncthreads();
  }
#pragma unroll
  for (int mt = 0; mt < MTILES; mt++)
#pragma unroll
    for (int nt = 0; nt < NTILES; nt++)
#pragma unroll
      for (int r = 0; r < 4; r++) {
        int m = (w * MTILES + mt) * 16 + q * 4 + r;
        int n = nb * 64 + nt * 16 + l15;
        P[((size_t)s * 320 + m) * 4096 + n] = acc[mt][nt][r];
      }
}

// ---------------------------------------------------------------------------
// 9) reduce split-K partials + bias + relu -> bf16 activations
// ---------------------------------------------------------------------------
__global__ __launch_bounds__(256) void reduce_kernel(
    const float* __restrict__ P, const float* __restrict__ bias,
    uint16_t* __restrict__ X) {
  int i = blockIdx.x * 256 + threadIdx.x;
  if (i >= 320 * 4096) return;
  int n = i & 4095;
  float s = 0.0f;
#pragma unroll
  for (int j = 0; j < 8; j++) s += P[(size_t)j * 320 * 4096 + i];
  s += bias[n];
  s = fmaxf(s, 0.0f);
  X[i] = f2bf(s);
}

// ---------------------------------------------------------------------------
// 10a) combined head weight -> bf16 transposed Wh[112][4096]
//      n<21: cls_w col n; 21<=n<105: reg_w col n-21; n>=105: zero pad
// ---------------------------------------------------------------------------
__global__ __launch_bounds__(256) void headw_kernel(
    const float* __restrict__ cls_w, const float* __restrict__ reg_w,
    uint16_t* __restrict__ Wh) {
  int i = blockIdx.x * 256 + threadIdx.x;
  if (i >= 112 * 4096) return;
  int n = i >> 12, k = i & 4095;
  float v = 0.0f;
  if (n < 21) v = cls_w[k * 21 + n];
  else if (n < 105) v = reg_w[k * 84 + (n - 21)];
  Wh[i] = f2bf(v);
}

// ---------------------------------------------------------------------------
// 10b) head GEMM: logits[320][112] = X3[320][4096] @ Wh^T, split-K=8, no LDS
//      (A/B frags are contiguous 16B global loads; everything L2-resident)
// ---------------------------------------------------------------------------
#define HNT 7
__global__ __launch_bounds__(256) void headgemm_kernel(
    const uint16_t* __restrict__ X3, const uint16_t* __restrict__ Wh,
    float* __restrict__ HP) {
  const int s = blockIdx.x;  // split 0..7
  const int tid = threadIdx.x;
  const int w = tid >> 6, l = tid & 63, q = l >> 4, l15 = l & 15;
  f32x4 acc[MTILES][HNT];
#pragma unroll
  for (int i = 0; i < MTILES; i++)
#pragma unroll
    for (int j = 0; j < HNT; j++) acc[i][j] = (f32x4)0.0f;
#pragma unroll 4
  for (int kk = 0; kk < 16; kk++) {
    int k0 = s * 512 + kk * 32 + q * 8;
    short8 bfr[HNT];
#pragma unroll
    for (int nt = 0; nt < HNT; nt++)
      bfr[nt] = *(const short8*)(Wh + (size_t)(nt * 16 + l15) * 4096 + k0);
#pragma unroll
    for (int mt = 0; mt < MTILES; mt++) {
      short8 afr =
          *(const short8*)(X3 + (size_t)((w * MTILES + mt) * 16 + l15) * 4096 + k0);
#pragma unroll
      for (int nt = 0; nt < HNT; nt++)
        acc[mt][nt] =
            __builtin_amdgcn_mfma_f32_16x16x32_bf16(afr, bfr[nt], acc[mt][nt], 0, 0, 0);
    }
  }
#pragma unroll
  for (int mt = 0; mt < MTILES; mt++)
#pragma unroll
    for (int nt = 0; nt < HNT; nt++)
#pragma unroll
      for (int r = 0; r < 4; r++) {
        int m = (w * MTILES + mt) * 16 + q * 4 + r;
        int n = nt * 16 + l15;
        HP[((size_t)s * 320 + m) * 112 + n] = acc[mt][nt][r];
      }
}

// ---------------------------------------------------------------------------
// 10c) head epilogue: reduce split-K, bias+std, softmax + box decode
// ---------------------------------------------------------------------------
__global__ __launch_bounds__(128) void head_epi_kernel(
    const float* __restrict__ HP, const float* __restrict__ cls_b,
    const float* __restrict__ reg_b, const float4* __restrict__ keep_xywh,
    float* __restrict__ out) {
  int m = blockIdx.x;
  int tid = threadIdx.x;
  __shared__ float row[112];
  if (tid < 105) {
    float v = 0.0f;
#pragma unroll
    for (int s = 0; s < 8; s++) v += HP[((size_t)s * 320 + m) * 112 + tid];
    if (tid < 21) {
      v += cls_b[tid];
    } else {
      int j = tid - 21;
      v += reg_b[j];
      v *= ((j & 3) < 2) ? 0.1f : 0.2f;
    }
    row[tid] = v;
  }
  __syncthreads();
  if (tid < 105) {
    float val;
    if (tid < 21) {
      float mx = row[0];
      for (int j = 1; j < 21; j++) mx = fmaxf(mx, row[j]);
      float sum = 0.0f;
      for (int j = 0; j < 21; j++) sum += expf(row[j] - mx);
      val = expf(row[tid] - mx) / sum;
    } else {
      int j = tid - 21;
      int comp = j & 3;
      int cls = j >> 2;
      float r0 = row[21 + cls * 4 + 0];
      float r1 = row[21 + cls * 4 + 1];
      float r2 = row[21 + cls * 4 + 2];
      float r3 = row[21 + cls * 4 + 3];
      float4 sb = keep_xywh[m];
      float x = sb.x + r0 * sb.z;
      float y = sb.y + r1 * sb.w;
      if (comp == 0) val = x;
      else if (comp == 1) val = y;
      else if (comp == 2) val = x + sb.z * expf(r2);
      else val = y + sb.w * expf(r3);
      val = fminf(fmaxf(val, 0.0f), 800.0f);
    }
    out[(size_t)m * 105 + tid] = val;
  }
}

// ---------------------------------------------------------------------------
// launch
// ---------------------------------------------------------------------------
extern "C" void kernel_launch(void* const* d_in, const int* in_sizes, int n_in,
                              void* d_out, int out_size, void* d_ws, size_t ws_size,
                              hipStream_t stream) {
  const float* feat      = (const float*)d_in[0];
  const float* proposals = (const float*)d_in[1];
  const float* scores    = (const float*)d_in[2];
  const float* fc1_w     = (const float*)d_in[3];
  const float* fc1_b     = (const float*)d_in[4];
  const float* fc2_w     = (const float*)d_in[5];
  const float* fc2_b     = (const float*)d_in[6];
  const float* cls_w     = (const float*)d_in[7];
  const float* cls_b     = (const float*)d_in[8];
  const float* reg_w     = (const float*)d_in[9];
  const float* reg_b     = (const float*)d_in[10];
  float* out = (float*)d_out;

  char* ws = (char*)d_ws;
  size_t off = 0;
  auto alloc = [&](size_t bytes) -> void* {
    void* p = ws + off;
    off = (off + bytes + 255) & ~(size_t)255;
    return p;
  };
  uint32_t* keys      = (uint32_t*)alloc(22500 * 4);
  int*      misc      = (int*)alloc(256);           // [0]=cutoff, [1]=counter
  uint64_t* sortbuf   = (uint64_t*)alloc(8192 * 8);
  int*      sorted_idx= (int*)alloc(6000 * 4);
  float4*   sxyxy     = (float4*)alloc(6000 * 16);
  float4*   sxywh     = (float4*)alloc(6000 * 16);
  float4*   keep_xyxy = (float4*)alloc(300 * 16);
  float4*   keep_xywh = (float4*)alloc(300 * 16);
  uint16_t* Abuf      = (uint16_t*)alloc((size_t)320 * 25088 * 2);
  uint16_t* X2        = (uint16_t*)alloc((size_t)320 * 4096 * 2);
  uint16_t* X3        = (uint16_t*)alloc((size_t)320 * 4096 * 2);
  uint16_t* Wh        = (uint16_t*)alloc((size_t)112 * 4096 * 2);
  float*    HP        = (float*)alloc((size_t)8 * 320 * 112 * 4);
  float*    partials  = (float*)alloc((size_t)8 * 320 * 4096 * 4);
  uint32_t* cutoff    = (uint32_t*)misc;
  int*      counter   = misc + 1;
  // IoU bit-matrix (4.5 MB) aliases the split-K partials buffer: M is dead
  // before the first gemm_kernel writes partials (same stream, sequential).
  uint32_t* M = (uint32_t*)partials;

  prep_kernel<<<88, 256, 0, stream>>>(proposals, scores, keys, sortbuf, counter);
  select_kernel<<<1, 1024, 0, stream>>>(keys, cutoff);
  compact_kernel<<<88, 256, 0, stream>>>(keys, cutoff, sortbuf, counter);
  sort_kernel<<<1, 1024, 0, stream>>>(sortbuf, sorted_idx);
  gather_kernel<<<24, 256, 0, stream>>>(proposals, sorted_idx, sxyxy, sxywh);
  ioumat_kernel<<<4407, 256, 0, stream>>>(sxyxy, M);
  nms_reduce_kernel<<<1, 256, 0, stream>>>(M, sxyxy, sxywh, keep_xyxy, keep_xywh);
  roi_kernel<<<320, 256, 0, stream>>>(feat, keep_xyxy, Abuf);
  headw_kernel<<<1792, 256, 0, stream>>>(cls_w, reg_w, Wh);  // overlaps nothing it depends on
  gemm_kernel<<<dim3(64, 8), 256, 0, stream>>>(Abuf, fc1_w, partials, 25088, 8);
  reduce_kernel<<<5120, 256, 0, stream>>>(partials, fc1_b, X2);
  gemm_kernel<<<dim3(64, 8), 256, 0, stream>>>(X2, fc2_w, partials, 4096, 8);
  reduce_kernel<<<5120, 256, 0, stream>>>(partials, fc2_b, X3);
  headgemm_kernel<<<8, 256, 0, stream>>>(X3, Wh, HP);
  head_epi_kernel<<<300, 128, 0, stream>>>(HP, cls_b, reg_b, keep_xywh, out);
}

// Round 4
// 1165.308 us; speedup vs baseline: 1.4312x; 1.0435x over previous
//
#include <hip/hip_runtime.h>
#include <stdint.h>

// ---------------------------------------------------------------------------
// FasterRCNN head on MI355X.
// Pipeline: mask scores -> radix-select 6000th -> compact -> rank-by-counting
//           (replaces bitonic sort) -> IoU bit-matrix + bitmask greedy NMS
//           -> ROIAlign (bf16) -> fc1/fc2 (bf16 MFMA, split-K=16) -> head
//           GEMM (MFMA, no-LDS) -> softmax + decode epilogue.
// ---------------------------------------------------------------------------

#define NEGV -1e30f
#define SPLITS 16

typedef __attribute__((ext_vector_type(8))) short short8;
typedef __attribute__((ext_vector_type(4))) float f32x4;

__device__ __forceinline__ uint16_t f2bf(float f) {
  uint32_t u = __builtin_bit_cast(uint32_t, f);
  u = (u + 0x7FFFu + ((u >> 16) & 1u)) >> 16;
  return (uint16_t)u;
}
__device__ __forceinline__ float bf2f(uint16_t h) {
  return __builtin_bit_cast(float, ((uint32_t)h) << 16);
}
// monotone float -> uint32 key (order-preserving for all finite floats)
__device__ __forceinline__ uint32_t fkey(float f) {
  uint32_t u = __builtin_bit_cast(uint32_t, f);
  return (u & 0x80000000u) ? ~u : (u | 0x80000000u);
}

// ---------------------------------------------------------------------------
// 1) score mask + key build; also init sort buffer + atomic counter
// ---------------------------------------------------------------------------
__global__ __launch_bounds__(256) void prep_kernel(
    const float* __restrict__ proposals, const float* __restrict__ scores,
    uint32_t* __restrict__ keys, uint64_t* __restrict__ sortbuf,
    int* __restrict__ counter) {
  int i = blockIdx.x * 256 + threadIdx.x;
  if (i < 8192) sortbuf[i] = 0ULL;  // sentinel: below every real entry
  if (i == 0) *counter = 0;
  if (i < 22500) {
    float w = proposals[i * 4 + 2], h = proposals[i * 4 + 3];
    float s = scores[i];
    s = (w < 16.0f || h < 16.0f) ? NEGV : s;
    keys[i] = fkey(s);
  }
}

// ---------------------------------------------------------------------------
// 2) radix select: exact key value of the 6000th largest
//    (parallel suffix-scan replaces thread-0 serial bin walk)
// ---------------------------------------------------------------------------
__global__ __launch_bounds__(1024) void select_kernel(
    const uint32_t* __restrict__ keys, uint32_t* __restrict__ cutoff) {
  __shared__ uint32_t hist[256];
  __shared__ int ssum[256];
  __shared__ uint32_t s_prefix;
  __shared__ int s_remaining;
  int tid = threadIdx.x;
  if (tid == 0) { s_prefix = 0; s_remaining = 6000; }
  __syncthreads();
  for (int round = 0; round < 4; round++) {
    int shift = 24 - round * 8;
    if (tid < 256) hist[tid] = 0;
    __syncthreads();
    uint32_t prefix = s_prefix;
    uint32_t pmask = (round == 0) ? 0u : (0xFFFFFFFFu << (shift + 8));
    for (int i = tid; i < 22500; i += 1024) {
      uint32_t kv = keys[i];
      if ((kv & pmask) == (prefix & pmask))
        atomicAdd(&hist[(kv >> shift) & 255u], 1u);
    }
    __syncthreads();
    if (tid < 256) ssum[tid] = (int)hist[tid];
    __syncthreads();
    // suffix sum: ssum[b] = sum_{b'>=b} hist[b']
    for (int offs = 1; offs < 256; offs <<= 1) {
      int v = 0;
      if (tid < 256 && tid + offs < 256) v = ssum[tid + offs];
      __syncthreads();
      if (tid < 256) ssum[tid] += v;
      __syncthreads();
    }
    int rem = s_remaining;
    __syncthreads();
    if (tid < 256) {
      int s_here = ssum[tid];
      int s_next = (tid == 255) ? 0 : ssum[tid + 1];
      if (s_here >= rem && s_next < rem) {  // unique crossing bin
        s_prefix = prefix | ((uint32_t)tid << shift);
        s_remaining = rem - s_next;
      }
    }
    __syncthreads();
  }
  if (tid == 0) *cutoff = s_prefix;
}

// ---------------------------------------------------------------------------
// 3) compact all entries with key >= cutoff  (6000 + a few ties at most)
// ---------------------------------------------------------------------------
__global__ __launch_bounds__(256) void compact_kernel(
    const uint32_t* __restrict__ keys, const uint32_t* __restrict__ cutoff,
    uint64_t* __restrict__ sortbuf, int* __restrict__ counter) {
  int i = blockIdx.x * 256 + threadIdx.x;
  if (i >= 22500) return;
  uint32_t kv = keys[i];
  if (kv >= *cutoff) {
    int p = atomicAdd(counter, 1);
    if (p < 8192)
      sortbuf[p] = ((uint64_t)kv << 32) | (uint32_t)(~(uint32_t)i);
  }
}

// ---------------------------------------------------------------------------
// 4) rank-by-counting over 8192 composites (desc) -> scatter top 6000.
//    Composite (key<<32)|~idx is unique; rank = #{j: comp_j > comp_i}.
//    Exactly the bitonic sort's order (key desc, idx asc), 128 parallel blocks.
// ---------------------------------------------------------------------------
__global__ __launch_bounds__(256) void rank_kernel(
    const uint64_t* __restrict__ sortbuf, int* __restrict__ sorted_idx) {
  __shared__ uint64_t comp[8192];  // 64 KB
  __shared__ int cnt[64];
  int tid = threadIdx.x;
  for (int i = tid; i < 8192; i += 256) comp[i] = sortbuf[i];
  if (tid < 64) cnt[tid] = 0;
  __syncthreads();
  int il = tid & 63;        // which of this block's 64 elements
  int sub = tid >> 6;       // wave id -> j-quarter
  uint64_t my = comp[blockIdx.x * 64 + il];
  const uint64_t* base = &comp[sub * 2048];
  int c = 0;
#pragma unroll 4
  for (int j = 0; j < 2048; j += 2) {  // wave-uniform LDS broadcast reads
    uint64_t a = base[j], b = base[j + 1];
    c += (a > my) ? 1 : 0;
    c += (b > my) ? 1 : 0;
  }
  atomicAdd(&cnt[il], c);
  __syncthreads();
  if (tid < 64) {
    int rank = cnt[tid];
    uint64_t m2 = comp[blockIdx.x * 64 + tid];
    if (m2 != 0ULL && rank < 6000)
      sorted_idx[rank] = (int)(~(uint32_t)(m2 & 0xFFFFFFFFull));
  }
}

// ---------------------------------------------------------------------------
// 5) gather sorted boxes: xywh + xyxy
// ---------------------------------------------------------------------------
__global__ __launch_bounds__(256) void gather_kernel(
    const float* __restrict__ proposals, const int* __restrict__ sorted_idx,
    float4* __restrict__ sxyxy, float4* __restrict__ sxywh) {
  int i = blockIdx.x * 256 + threadIdx.x;
  if (i >= 6000) return;
  int oi = sorted_idx[i];
  float x = proposals[oi * 4 + 0], y = proposals[oi * 4 + 1];
  float w = proposals[oi * 4 + 2], h = proposals[oi * 4 + 3];
  sxywh[i] = make_float4(x, y, w, h);
  sxyxy[i] = make_float4(x, y, x + w, y + h);  // single adds: exact vs ref
}

// ---------------------------------------------------------------------------
// 6a) IoU suppression bit-matrix: M[j][w] bit b = IoU(box j, box w*32+b) > 0.7
// ---------------------------------------------------------------------------
__global__ __launch_bounds__(256) void ioumat_kernel(
    const float4* __restrict__ boxes, uint32_t* __restrict__ M) {
#pragma clang fp contract(off)
  int idx = blockIdx.x * 256 + threadIdx.x;  // j*188 + w
  if (idx >= 6000 * 188) return;
  int j = idx / 188;
  int w = idx - j * 188;
  float4 bb = boxes[j];
  float ba = (bb.z - bb.x) * (bb.w - bb.y);
  int base = w * 32;
  int lim = min(6000 - base, 32);
  uint32_t bits = 0;
  for (int b = 0; b < lim; b++) {
    float4 ob = boxes[base + b];
    float xx1 = fmaxf(bb.x, ob.x);
    float yy1 = fmaxf(bb.y, ob.y);
    float xx2 = fminf(bb.z, ob.z);
    float yy2 = fminf(bb.w, ob.w);
    float inter = fmaxf(xx2 - xx1, 0.0f) * fmaxf(yy2 - yy1, 0.0f);
    float oa = (ob.z - ob.x) * (ob.w - ob.y);
    float iou = inter / (ba + oa - inter + 1e-9f);
    if (iou > 0.7f) bits |= (1u << b);
  }
  M[idx] = bits;
}

// ---------------------------------------------------------------------------
// 6b) bitmask greedy reduce with LDS-preloaded diagonal 64x64 blocks.
// ---------------------------------------------------------------------------
__global__ __launch_bounds__(256) void nms_reduce_kernel(
    const uint32_t* __restrict__ M, const float4* __restrict__ sxyxy,
    const float4* __restrict__ sxywh, float4* __restrict__ keep_xyxy,
    float4* __restrict__ keep_xywh) {
  __shared__ uint64_t diag[94 * 64];  // 48 KB: intra-chunk suppression rows
  __shared__ uint32_t remv[188];
  __shared__ int keeps[300];
  __shared__ int s_ck[64];
  __shared__ int s_nk, s_nck;
  int tid = threadIdx.x;
  for (int t = tid; t < 94 * 64; t += 256) {
    int c = t >> 6, r = t & 63;
    int row = c * 64 + r;
    uint64_t v = 0;
    if (row < 6000)
      v = (uint64_t)M[(size_t)row * 188 + 2 * c] |
          ((uint64_t)M[(size_t)row * 188 + 2 * c + 1] << 32);
    diag[t] = v;
  }
  if (tid < 188) remv[tid] = (tid == 187) ? 0xFFFF0000u : 0u;  // bits>=6000 off
  if (tid == 0) { s_nk = 0; s_nck = 0; }
  __syncthreads();
  for (int c = 0; c < 94; c++) {
    if (tid < 64) {
      uint64_t myrow = diag[c * 64 + tid];
      uint32_t lo = (uint32_t)myrow, hi = (uint32_t)(myrow >> 32);
      uint64_t alive =
          ~(((uint64_t)remv[2 * c + 1] << 32) | (uint64_t)remv[2 * c]);
      int nk = s_nk;
      int nck = 0;
      while (alive != 0 && nk < 300) {
        int b = (int)__builtin_ctzll(alive);
        int j = c * 64 + b;
        if (tid == 0) { keeps[nk] = j; s_ck[nck] = j; }
        nk++;
        nck++;
        uint64_t rb = ((uint64_t)(uint32_t)__shfl((int)hi, b, 64) << 32) |
                      (uint64_t)(uint32_t)__shfl((int)lo, b, 64);
        alive &= ~rb;
        alive &= ~(1ull << b);  // self
      }
      if (tid == 0) { s_nk = nk; s_nck = nck; }
    }
    __syncthreads();
    int nck = s_nck;
    // parallel OR: all kept rows x 188 words at once (loads overlap)
    for (int i = tid; i < nck * 188; i += 256) {
      int r = i / 188;
      int wd = i - r * 188;
      atomicOr(&remv[wd], M[(size_t)s_ck[r] * 188 + wd]);
    }
    __syncthreads();
    if (s_nk >= 300) break;
  }
  __syncthreads();
  int nk = s_nk;
  for (int i = tid; i < 300; i += 256) {
    int kp = (i < nk) ? keeps[i] : 0;  // ref argmax-over-all-NEG fallback
    keep_xyxy[i] = sxyxy[kp];
    keep_xywh[i] = sxywh[kp];
  }
}

// ---------------------------------------------------------------------------
// 7) ROIAlign -> A matrix bf16 [320][25088]  (rows 300..319 zero pad)
// ---------------------------------------------------------------------------
__global__ __launch_bounds__(256) void roi_kernel(
    const float* __restrict__ feat, const float4* __restrict__ keep_xyxy,
    uint16_t* __restrict__ A) {
  int r = blockIdx.x;
  int tid = threadIdx.x;
  uint16_t* out = A + (size_t)r * 25088;
  if (r >= 300) {
    for (int k = tid; k < 25088; k += 256) out[k] = 0;
    return;
  }
  __shared__ int xi0[14], xi1[14], yi0[14], yi1[14];
  __shared__ float wxs[14], wys[14];
  if (tid < 28) {
    int axis = tid / 14;  // 0 = x, 1 = y
    int t = tid % 14;
    int g = t >> 1, sxi = t & 1;
    float4 box = keep_xyxy[r];
    float lo = (axis ? box.y : box.x) * 0.0625f;
    float hi = (axis ? box.w : box.z) * 0.0625f;
    float bsz = (hi - lo) / 7.0f;
    float sub = ((float)sxi + 0.5f) * 0.5f;  // 0.25 / 0.75 exact
    float coord = lo + ((float)g + sub) * bsz;
    float f = floorf(coord);
    float frac = coord - f;
    int i0 = (int)f;
    i0 = min(max(i0, 0), 49);
    int i1 = min(i0 + 1, 49);
    if (axis == 0) { xi0[t] = i0; xi1[t] = i1; wxs[t] = frac; }
    else           { yi0[t] = i0; yi1[t] = i1; wys[t] = frac; }
  }
  __syncthreads();
  for (int k = tid; k < 25088; k += 256) {
    int c = k / 49;
    int pos = k - c * 49;
    int py = pos / 7, px = pos - py * 7;
    const float* fc = feat + (size_t)c * 2500;
    float val = 0.0f;
#pragma unroll
    for (int sy = 0; sy < 2; sy++) {
      int iy = py * 2 + sy;
      float wy = wys[iy];
      int y0 = yi0[iy], y1 = yi1[iy];
#pragma unroll
      for (int sx = 0; sx < 2; sx++) {
        int ix = px * 2 + sx;
        float wx = wxs[ix];
        int x0 = xi0[ix], x1 = xi1[ix];
        float v00 = fc[y0 * 50 + x0], v01 = fc[y0 * 50 + x1];
        float v10 = fc[y1 * 50 + x0], v11 = fc[y1 * 50 + x1];
        val += v00 * (1.0f - wy) * (1.0f - wx) + v01 * (1.0f - wy) * wx +
               v10 * wy * (1.0f - wx) + v11 * wy * wx;
      }
    }
    out[k] = f2bf(val * 0.25f);
  }
}

// ---------------------------------------------------------------------------
// 8) split-K bf16 MFMA GEMM:  P[s] += A[320,K_chunk] * W[K_chunk, 4096-col64]
// ---------------------------------------------------------------------------
#define MTILES 5
#define NTILES 4
__global__ __launch_bounds__(256) void gemm_kernel(
    const uint16_t* __restrict__ A, const float* __restrict__ W,
    float* __restrict__ P, int K, int S) {
  __shared__ uint16_t As[320 * 32];  // packed [m][32], 64B rows
  __shared__ uint16_t Bs[64 * 40];   // [n][k] 80B rows (32 used + 8 pad)
  const int nb = blockIdx.x;
  const int s = blockIdx.y;
  const int kchunk = K / S;
  const int steps = kchunk >> 5;
  const int k0base = s * kchunk;
  const int tid = threadIdx.x;
  const int w = tid >> 6;
  const int l = tid & 63;
  const int q = l >> 4;
  const int l15 = l & 15;

  f32x4 acc[MTILES][NTILES];
#pragma unroll
  for (int i = 0; i < MTILES; i++)
#pragma unroll
    for (int j = 0; j < NTILES; j++) acc[i][j] = (f32x4)0.0f;

  const int ng = (tid & 15) << 2;  // n group of 4 for B staging
  const int kp = tid >> 4;         // k-pair 0..15

  for (int kk = 0; kk < steps; kk++) {
    const int k0 = k0base + (kk << 5);
#pragma unroll
    for (int t = 0; t < 5; t++) {
      int cidx = w * 320 + t * 64 + l;  // 16B chunk id
      int m = cidx >> 2;
      int co = (cidx & 3) << 3;         // ushort offset in row
      const uint16_t* gp = A + (size_t)m * K + k0 + co;
      __builtin_amdgcn_global_load_lds(
          (const __attribute__((address_space(1))) void*)gp,
          (__attribute__((address_space(3))) void*)(As + (w * 320 + t * 64) * 8),
          16, 0, 0);
    }
    {
      const float* wp = W + (size_t)(k0 + 2 * kp) * 4096 + nb * 64 + ng;
      f32x4 f0 = *(const f32x4*)wp;
      f32x4 f1 = *(const f32x4*)(wp + 4096);
#pragma unroll
      for (int j = 0; j < 4; j++) {
        uint32_t v = (uint32_t)f2bf(f0[j]) | ((uint32_t)f2bf(f1[j]) << 16);
        *(uint32_t*)&Bs[(ng + j) * 40 + 2 * kp] = v;
      }
    }
    __syncthreads();
    short8 bfr[NTILES];
#pragma unroll
    for (int nt = 0; nt < NTILES; nt++)
      bfr[nt] = *(const short8*)&Bs[(nt * 16 + l15) * 40 + q * 8];
#pragma unroll
    for (int mt = 0; mt < MTILES; mt++) {
      int mrow = (w * MTILES + mt) * 16 + l15;
      short8 afr = *(const short8*)&As[mrow * 32 + q * 8];
#pragma unroll
      for (int nt = 0; nt < NTILES; nt++)
        acc[mt][nt] =
            __builtin_amdgcn_mfma_f32_16x16x32_bf16(afr, bfr[nt], acc[mt][nt], 0, 0, 0);
    }
    __syncthreads();
  }
#pragma unroll
  for (int mt = 0; mt < MTILES; mt++)
#pragma unroll
    for (int nt = 0; nt < NTILES; nt++)
#pragma unroll
      for (int r = 0; r < 4; r++) {
        int m = (w * MTILES + mt) * 16 + q * 4 + r;
        int n = nb * 64 + nt * 16 + l15;
        P[((size_t)s * 320 + m) * 4096 + n] = acc[mt][nt][r];
      }
}

// ---------------------------------------------------------------------------
// 9) reduce split-K partials + bias + relu -> bf16 activations
// ---------------------------------------------------------------------------
__global__ __launch_bounds__(256) void reduce_kernel(
    const float* __restrict__ P, const float* __restrict__ bias,
    uint16_t* __restrict__ X) {
  int i = blockIdx.x * 256 + threadIdx.x;
  if (i >= 320 * 4096) return;
  int n = i & 4095;
  float s = 0.0f;
#pragma unroll
  for (int j = 0; j < SPLITS; j++) s += P[(size_t)j * 320 * 4096 + i];
  s += bias[n];
  s = fmaxf(s, 0.0f);
  X[i] = f2bf(s);
}

// ---------------------------------------------------------------------------
// 10a) combined head weight -> bf16 transposed Wh[112][4096]
// ---------------------------------------------------------------------------
__global__ __launch_bounds__(256) void headw_kernel(
    const float* __restrict__ cls_w, const float* __restrict__ reg_w,
    uint16_t* __restrict__ Wh) {
  int i = blockIdx.x * 256 + threadIdx.x;
  if (i >= 112 * 4096) return;
  int n = i >> 12, k = i & 4095;
  float v = 0.0f;
  if (n < 21) v = cls_w[k * 21 + n];
  else if (n < 105) v = reg_w[k * 84 + (n - 21)];
  Wh[i] = f2bf(v);
}

// ---------------------------------------------------------------------------
// 10b) head GEMM: logits[320][112] = X3[320][4096] @ Wh^T, split-K=8, no LDS
// ---------------------------------------------------------------------------
#define HNT 7
__global__ __launch_bounds__(256) void headgemm_kernel(
    const uint16_t* __restrict__ X3, const uint16_t* __restrict__ Wh,
    float* __restrict__ HP) {
  const int s = blockIdx.x;  // split 0..7
  const int tid = threadIdx.x;
  const int w = tid >> 6, l = tid & 63, q = l >> 4, l15 = l & 15;
  f32x4 acc[MTILES][HNT];
#pragma unroll
  for (int i = 0; i < MTILES; i++)
#pragma unroll
    for (int j = 0; j < HNT; j++) acc[i][j] = (f32x4)0.0f;
#pragma unroll 4
  for (int kk = 0; kk < 16; kk++) {
    int k0 = s * 512 + kk * 32 + q * 8;
    short8 bfr[HNT];
#pragma unroll
    for (int nt = 0; nt < HNT; nt++)
      bfr[nt] = *(const short8*)(Wh + (size_t)(nt * 16 + l15) * 4096 + k0);
#pragma unroll
    for (int mt = 0; mt < MTILES; mt++) {
      short8 afr =
          *(const short8*)(X3 + (size_t)((w * MTILES + mt) * 16 + l15) * 4096 + k0);
#pragma unroll
      for (int nt = 0; nt < HNT; nt++)
        acc[mt][nt] =
            __builtin_amdgcn_mfma_f32_16x16x32_bf16(afr, bfr[nt], acc[mt][nt], 0, 0, 0);
    }
  }
#pragma unroll
  for (int mt = 0; mt < MTILES; mt++)
#pragma unroll
    for (int nt = 0; nt < HNT; nt++)
#pragma unroll
      for (int r = 0; r < 4; r++) {
        int m = (w * MTILES + mt) * 16 + q * 4 + r;
        int n = nt * 16 + l15;
        HP[((size_t)s * 320 + m) * 112 + n] = acc[mt][nt][r];
      }
}

// ---------------------------------------------------------------------------
// 10c) head epilogue: reduce split-K, bias+std, softmax + box decode
// ---------------------------------------------------------------------------
__global__ __launch_bounds__(128) void head_epi_kernel(
    const float* __restrict__ HP, const float* __restrict__ cls_b,
    const float* __restrict__ reg_b, const float4* __restrict__ keep_xywh,
    float* __restrict__ out) {
  int m = blockIdx.x;
  int tid = threadIdx.x;
  __shared__ float row[112];
  if (tid < 105) {
    float v = 0.0f;
#pragma unroll
    for (int s = 0; s < 8; s++) v += HP[((size_t)s * 320 + m) * 112 + tid];
    if (tid < 21) {
      v += cls_b[tid];
    } else {
      int j = tid - 21;
      v += reg_b[j];
      v *= ((j & 3) < 2) ? 0.1f : 0.2f;
    }
    row[tid] = v;
  }
  __syncthreads();
  if (tid < 105) {
    float val;
    if (tid < 21) {
      float mx = row[0];
      for (int j = 1; j < 21; j++) mx = fmaxf(mx, row[j]);
      float sum = 0.0f;
      for (int j = 0; j < 21; j++) sum += expf(row[j] - mx);
      val = expf(row[tid] - mx) / sum;
    } else {
      int j = tid - 21;
      int comp = j & 3;
      int cls = j >> 2;
      float r0 = row[21 + cls * 4 + 0];
      float r1 = row[21 + cls * 4 + 1];
      float r2 = row[21 + cls * 4 + 2];
      float r3 = row[21 + cls * 4 + 3];
      float4 sb = keep_xywh[m];
      float x = sb.x + r0 * sb.z;
      float y = sb.y + r1 * sb.w;
      if (comp == 0) val = x;
      else if (comp == 1) val = y;
      else if (comp == 2) val = x + sb.z * expf(r2);
      else val = y + sb.w * expf(r3);
      val = fminf(fmaxf(val, 0.0f), 800.0f);
    }
    out[(size_t)m * 105 + tid] = val;
  }
}

// ---------------------------------------------------------------------------
// launch
// ---------------------------------------------------------------------------
extern "C" void kernel_launch(void* const* d_in, const int* in_sizes, int n_in,
                              void* d_out, int out_size, void* d_ws, size_t ws_size,
                              hipStream_t stream) {
  const float* feat      = (const float*)d_in[0];
  const float* proposals = (const float*)d_in[1];
  const float* scores    = (const float*)d_in[2];
  const float* fc1_w     = (const float*)d_in[3];
  const float* fc1_b     = (const float*)d_in[4];
  const float* fc2_w     = (const float*)d_in[5];
  const float* fc2_b     = (const float*)d_in[6];
  const float* cls_w     = (const float*)d_in[7];
  const float* cls_b     = (const float*)d_in[8];
  const float* reg_w     = (const float*)d_in[9];
  const float* reg_b     = (const float*)d_in[10];
  float* out = (float*)d_out;

  char* ws = (char*)d_ws;
  size_t off = 0;
  auto alloc = [&](size_t bytes) -> void* {
    void* p = ws + off;
    off = (off + bytes + 255) & ~(size_t)255;
    return p;
  };
  uint32_t* keys      = (uint32_t*)alloc(22500 * 4);
  int*      misc      = (int*)alloc(256);           // [0]=cutoff, [1]=counter
  uint64_t* sortbuf   = (uint64_t*)alloc(8192 * 8);
  int*      sorted_idx= (int*)alloc(6000 * 4);
  float4*   sxyxy     = (float4*)alloc(6000 * 16);
  float4*   sxywh     = (float4*)alloc(6000 * 16);
  float4*   keep_xyxy = (float4*)alloc(300 * 16);
  float4*   keep_xywh = (float4*)alloc(300 * 16);
  uint16_t* Abuf      = (uint16_t*)alloc((size_t)320 * 25088 * 2);
  uint16_t* X2        = (uint16_t*)alloc((size_t)320 * 4096 * 2);
  uint16_t* X3        = (uint16_t*)alloc((size_t)320 * 4096 * 2);
  uint16_t* Wh        = (uint16_t*)alloc((size_t)112 * 4096 * 2);
  float*    HP        = (float*)alloc((size_t)8 * 320 * 112 * 4);
  float*    partials  = (float*)alloc((size_t)SPLITS * 320 * 4096 * 4);
  uint32_t* cutoff    = (uint32_t*)misc;
  int*      counter   = misc + 1;
  // IoU bit-matrix (4.5 MB) aliases the split-K partials buffer: M is dead
  // before the first gemm_kernel writes partials (same stream, sequential).
  uint32_t* M = (uint32_t*)partials;

  prep_kernel<<<88, 256, 0, stream>>>(proposals, scores, keys, sortbuf, counter);
  select_kernel<<<1, 1024, 0, stream>>>(keys, cutoff);
  compact_kernel<<<88, 256, 0, stream>>>(keys, cutoff, sortbuf, counter);
  rank_kernel<<<128, 256, 0, stream>>>(sortbuf, sorted_idx);
  gather_kernel<<<24, 256, 0, stream>>>(proposals, sorted_idx, sxyxy, sxywh);
  ioumat_kernel<<<4407, 256, 0, stream>>>(sxyxy, M);
  nms_reduce_kernel<<<1, 256, 0, stream>>>(M, sxyxy, sxywh, keep_xyxy, keep_xywh);
  roi_kernel<<<320, 256, 0, stream>>>(feat, keep_xyxy, Abuf);
  headw_kernel<<<1792, 256, 0, stream>>>(cls_w, reg_w, Wh);
  gemm_kernel<<<dim3(64, SPLITS), 256, 0, stream>>>(Abuf, fc1_w, partials, 25088, SPLITS);
  reduce_kernel<<<5120, 256, 0, stream>>>(partials, fc1_b, X2);
  gemm_kernel<<<dim3(64, SPLITS), 256, 0, stream>>>(X2, fc2_w, partials, 4096, SPLITS);
  reduce_kernel<<<5120, 256, 0, stream>>>(partials, fc2_b, X3);
  headgemm_kernel<<<8, 256, 0, stream>>>(X3, Wh, HP);
  head_epi_kernel<<<300, 128, 0, stream>>>(HP, cls_b, reg_b, keep_xywh, out);
}